// Round 5
// baseline (637.897 us; speedup 1.0000x reference)
//
#include <hip/hip_runtime.h>
#include <hip/hip_bf16.h>

typedef __attribute__((ext_vector_type(4))) float floatx4;
typedef __attribute__((ext_vector_type(8))) short shortx8;

#define NB   16
#define CIN  256
#define COUT 256
#define KW   3
#define LL   4096
#define NR   5
#define QK   768    // CIN*KW
#define NP   65536  // NB*LL
#define LP   (LL + 2)   // xt rows per batch incl 2-row causal zero pad

#define AS1 __attribute__((address_space(1)))
#define AS3 __attribute__((address_space(3)))

static __device__ __forceinline__ void async_cp16(const __hip_bfloat16* g, short* l) {
    __builtin_amdgcn_global_load_lds((const AS1 unsigned int*)(const void*)g,
                                     (AS3 unsigned int*)(void*)l, 16, 0, 0);
}

static __device__ __forceinline__ unsigned short bf16bits(float f) {
    __hip_bfloat16 h = __float2bfloat16(f);
    return __builtin_bit_cast(unsigned short, h);
}

// ---------------- K1: merged pre-pass ----------------
// blocks [0,1024):  controller fr + x transpose -> xt (bf16, padded layout)
// blocks [1024,1984): weights -> bf16, m = (o>>4)*80 + r*16 + (o&15), q' = k*256+cin
// blocks [1984,1992): zero the 2-row causal pads of xt
__global__ void k_pre(const float* __restrict__ x, const float* __restrict__ bk,
                      const float* __restrict__ cw, const float* __restrict__ cb,
                      float* __restrict__ fr, __hip_bfloat16* __restrict__ xt,
                      __hip_bfloat16* __restrict__ wb) {
    int gid = blockIdx.x;
    int tid = threadIdx.x;
    if (gid >= 1984) {  // pad-zero: 8 blocks x 256 thr x ushort4 = 8192 elems
        int i4 = (gid - 1984) * 256 + tid;        // 0..2047
        int bb = i4 >> 7, off = (i4 & 127) * 4;   // 128 ushort4 per batch pad
        *(ushort4*)&xt[(size_t)bb * (LP * CIN) + off] = make_ushort4(0, 0, 0, 0);
        return;
    }
    if (gid >= 1024) {  // wprep: 960 blocks x 1024 elems
        int base = (gid - 1024) * 1024 + tid;
        #pragma unroll
        for (int j = 0; j < 4; ++j) {
            int i = base + j * 256;
            int m = i / QK, q = i - m * QK;
            int o = (m / 80) * 16 + (m & 15);
            int r = (m % 80) / 16;
            int k = q >> 8, cin = q & 255;
            wb[i] = __float2bfloat16(bk[((r * COUT + o) * CIN + cin) * KW + k]);
        }
        return;
    }
    // ---- controller + transpose, 64 positions/block ----
    __shared__ float xsh[68][133];     // cols l0-4..l0+63, cins of current half
    __shared__ float cws[QK * NR];
    __shared__ float part[4][64][NR];
    int p0 = gid * 64;
    int b = p0 >> 12, l0 = p0 & (LL - 1);
    int lane = tid & 63, wid = tid >> 6;
    for (int i = tid; i < QK * NR; i += 256) cws[i] = cw[i];
    float lg[NR] = {0.f, 0.f, 0.f, 0.f, 0.f};
    for (int ch = 0; ch < 2; ++ch) {
        __syncthreads();
        for (int i = tid; i < 128 * 17; i += 256) {
            int cl = i / 17, c4 = (i % 17) * 4;
            int gl = l0 - 4 + c4;
            float4 v = make_float4(0.f, 0.f, 0.f, 0.f);
            if (gl >= 0) v = *(const float4*)&x[((size_t)(b * CIN + ch * 128 + cl)) * LL + gl];
            xsh[c4 + 0][cl] = v.x;
            xsh[c4 + 1][cl] = v.y;
            xsh[c4 + 2][cl] = v.z;
            xsh[c4 + 3][cl] = v.w;
        }
        __syncthreads();
        // emit xt half: 64 pos x 128 cins (padded row layout: +2)
        #pragma unroll
        for (int j = 0; j < 8; ++j) {
            int i2 = tid + j * 256;
            int p = i2 >> 5, c4 = (i2 & 31) * 4;
            ushort4 u;
            u.x = bf16bits(xsh[p + 4][c4 + 0]);
            u.y = bf16bits(xsh[p + 4][c4 + 1]);
            u.z = bf16bits(xsh[p + 4][c4 + 2]);
            u.w = bf16bits(xsh[p + 4][c4 + 3]);
            *(ushort4*)&xt[((size_t)(b * LP + 2 + l0 + p)) * CIN + ch * 128 + c4] = u;
        }
        #pragma unroll 8
        for (int r = 0; r < 32; ++r) {
            int cl = wid * 32 + r;
            int cg = ch * 128 + cl;
            float x0 = xsh[lane + 2][cl], x1 = xsh[lane + 3][cl], x2 = xsh[lane + 4][cl];
            const float* w = &cws[cg * 3 * NR];
            #pragma unroll
            for (int n = 0; n < NR; ++n)
                lg[n] += x0 * w[n] + x1 * w[NR + n] + x2 * w[2 * NR + n];
        }
    }
    #pragma unroll
    for (int n = 0; n < NR; ++n) part[wid][lane][n] = lg[n];
    __syncthreads();
    if (tid < 64) {
        float l2[NR];
        #pragma unroll
        for (int n = 0; n < NR; ++n)
            l2[n] = cb[n] + part[0][tid][n] + part[1][tid][n] + part[2][tid][n] + part[3][tid][n];
        float m = l2[0];
        #pragma unroll
        for (int n = 1; n < NR; ++n) m = fmaxf(m, l2[n]);
        float e[NR], s = 0.f;
        #pragma unroll
        for (int n = 0; n < NR; ++n) { e[n] = __expf(l2[n] - m); s += e[n]; }
        float inv = 1.f / s;
        #pragma unroll
        for (int n = 0; n < NR; ++n) fr[(size_t)(p0 + tid) * NR + n] = e[n] * inv;
    }
}

// ---------------- K2: fused conv + mixture ----------------
// GEMM M=1280 (rule-in-M), N=65536, K=768. Block M=80 x N=256, 8 waves x N32.
// x-tile (only) in LDS, double-buffered, filled by global_load_lds (async DMA).
// A-frags read directly from global (L1/L2-resident 2MB), one-step reg double-buffer.
#define XS_CHUNKS 2064              // 258 rows * 8 swizzled 16B chunks
#define XS_SHORTS (XS_CHUNKS * 8)   // 16512 shorts per buffer
__global__ __launch_bounds__(512, 4)
void k_conv(const __hip_bfloat16* __restrict__ xt, const __hip_bfloat16* __restrict__ wb,
            const float* __restrict__ fr, const float* __restrict__ bias,
            float* __restrict__ out) {
    __shared__ __align__(16) short lds[2 * XS_SHORTS];  // 66,048 B
    __shared__ float bs[80];

    int g = blockIdx.x;
    int pt = ((g >> 7) << 3) | (g & 7);   // XCD swizzle: 16 y-blocks share one x-tile per XCD
    int y  = (g >> 3) & 15;
    int p0 = pt * 256;
    int m0 = y * 80, o0 = y * 16;
    int b = p0 >> 12, l0 = p0 & (LL - 1);
    int tid = threadIdx.x;
    int lane = tid & 63, wn = tid >> 6;   // 8 waves x N=32
    int quad = lane >> 4, l16 = lane & 15;

    const __hip_bfloat16* xpb = xt + (size_t)b * (LP * CIN);  // padded batch base

    if (tid < 80) bs[tid] = bias[(tid >> 4) * COUT + o0 + (tid & 15)];

    // B-frag LDS offsets (within one buffer); col chunk ^32 for csi=1, +1024 for nf=1
    int boffb[3];
    #pragma unroll
    for (int kh = 0; kh < 3; ++kh) {
        int row0 = wn * 32 + l16 + kh;
        boffb[kh] = row0 * 64 + (quad ^ (row0 & 7)) * 8;
    }
    const shortx8* wv = (const shortx8*)wb;
    int widx[NR];
    #pragma unroll
    for (int mf = 0; mf < NR; ++mf) widx[mf] = (m0 + mf * 16 + l16) * 96 + quad;

    floatx4 acc[NR][2];
    #pragma unroll
    for (int mf = 0; mf < NR; ++mf) {
        acc[mf][0] = (floatx4){0.f, 0.f, 0.f, 0.f};
        acc[mf][1] = (floatx4){0.f, 0.f, 0.f, 0.f};
    }

    auto load_x = [&](int h) {   // async DMA, rows l0..l0+257 (padded), cins [h*64,h*64+64)
        short* base = &lds[(h & 1) * XS_SHORTS];
        #pragma unroll
        for (int j = 0; j < 5; ++j) {
            int i = tid + j * 512;
            if (j < 4 || i < XS_CHUNKS) {
                int row = i >> 3, cg = (i & 7) ^ (row & 7);
                async_cp16(xpb + (size_t)(l0 + row) * CIN + h * 64 + cg * 8, base + i * 8);
            }
        }
    };
    shortx8 aP[NR], aQ[NR];
    auto load_a = [&](int s, shortx8* d) {  // s = h*6 + kh*2 + csi
        int h = s / 6, r = s - h * 6, kh = r >> 1, csi = r & 1;
        int qoff = kh * 32 + h * 8 + csi * 4;
        #pragma unroll
        for (int mf = 0; mf < NR; ++mf) d[mf] = wv[widx[mf] + qoff];
    };

    load_x(0);
    load_a(0, aP);
    #pragma unroll
    for (int h = 0; h < 4; ++h) {
        __syncthreads();              // x(h) DMA complete; phase h-1 readers done
        if (h < 3) load_x(h + 1);     // fills other buffer, in flight across this phase
        const short* base = &lds[(h & 1) * XS_SHORTS];
        #pragma unroll
        for (int r = 0; r < 6; ++r) {
            int s = h * 6 + r;
            shortx8* cur = (s & 1) ? aQ : aP;
            shortx8* nxt = (s & 1) ? aP : aQ;
            if (s < 23) load_a(s + 1, nxt);   // next-step A in flight during MFMAs
            int kh = r >> 1, xr = (r & 1) * 32;
            shortx8 bf0 = *(const shortx8*)&base[(boffb[kh]) ^ xr];
            shortx8 bf1 = *(const shortx8*)&base[(boffb[kh] + 1024) ^ xr];
            #pragma unroll
            for (int mf = 0; mf < NR; ++mf) {
                acc[mf][0] = __builtin_amdgcn_mfma_f32_16x16x32_bf16(cur[mf], bf0, acc[mf][0], 0, 0, 0);
                acc[mf][1] = __builtin_amdgcn_mfma_f32_16x16x32_bf16(cur[mf], bf1, acc[mf][1], 0, 0, 0);
            }
        }
    }

    // epilogue: out[b, o0+olo, l0+colp] = sum_r fr[p][r]*(acc[r] + bias[r][o])
    #pragma unroll
    for (int nf = 0; nf < 2; ++nf) {
        int colp = wn * 32 + nf * 16 + l16;
        const float* fp = fr + (size_t)(p0 + colp) * NR;
        float f0 = fp[0], f1 = fp[1], f2 = fp[2], f3 = fp[3], f4 = fp[4];
        #pragma unroll
        for (int j = 0; j < 4; ++j) {
            int olo = quad * 4 + j;
            float v = f0 * (acc[0][nf][j] + bs[0 * 16 + olo])
                    + f1 * (acc[1][nf][j] + bs[1 * 16 + olo])
                    + f2 * (acc[2][nf][j] + bs[2 * 16 + olo])
                    + f3 * (acc[3][nf][j] + bs[3 * 16 + olo])
                    + f4 * (acc[4][nf][j] + bs[4 * 16 + olo]);
            out[((size_t)(b * COUT + o0 + olo)) * LL + l0 + colp] = v;
        }
    }
}

extern "C" void kernel_launch(void* const* d_in, const int* in_sizes, int n_in,
                              void* d_out, int out_size, void* d_ws, size_t ws_size,
                              hipStream_t stream) {
    const float* x  = (const float*)d_in[0];
    const float* bk = (const float*)d_in[1];
    const float* bb = (const float*)d_in[2];
    const float* cw = (const float*)d_in[3];
    const float* cb = (const float*)d_in[4];
    float* out = (float*)d_out;

    char* ws = (char*)d_ws;
    __hip_bfloat16* xt = (__hip_bfloat16*)ws;                          // 16*4098*256*2 = 33,570,816 B
    __hip_bfloat16* wb = (__hip_bfloat16*)(ws + 33570816);             //  1,966,080 B
    float*          fr = (float*)(ws + 33570816 + 1966080);            //  1,310,720 B

    k_pre<<<dim3(1992), dim3(256), 0, stream>>>(x, bk, cw, cb, fr, xt, wb);
    k_conv<<<dim3(NP / 256 * (COUT / 16)), dim3(512), 0, stream>>>(xt, wb, fr, bb, out);
}